// Round 8
// baseline (112.194 us; speedup 1.0000x reference)
//
#include <hip/hip_runtime.h>
#include <math.h>

// HarmonicCQT via f16 MFMA: out[b,t,k] = |sum_n xpad[t*512+n] * (kr[k,n]+i*ki[k,n])|
//
// R21: R20 + 4-chunk (128-col) K-steps. R20's coalesced-swizzled A staging
// (-12us, model-confirmed) left the barrier-drain cadence as the cost: ~18.4k
// WG-iterations, each a vmcnt(0)+barrier drain around only 16 MFMAs. Doubling
// the K-extent per stage halves drain events and doubles MFMA per drain
// (32/wave), LDS 2x16KB (5 WG/CU cap, grid 3.3/CU). Slice lengths 48/40/24
// are all divisible by 8 -> U/V step-pair structure and cw0 guards stay
// exact; chunk order unchanged -> bit-identical accumulation.
//
// A staging (per 64x128 tile): linear unit u = round*256+wave*64+lane ->
// LDS (row=u>>4, c16_dest=u&15); global src c16_src=(u&15)^(row&7) -- each
// 16-lane group = one 256B row segment (two 128B lines, line-aligned; XOR
// flips low 3 bits only, stays within each line). MFMA A-read at
// unit (cc*4+q)^(mm&7), row stride 256B. B in registers, U/V ping-pong
// prefetched one phase ahead (cross-barrier), sched_barrier-pinned.
//
// Path P, 3 dispatches, NO atomics:
//   1. prep_fused   : audio->f16 xp + B-fragment pack
//   2. cqt_mfma_t<true> : pipelined MFMA, 64 frames/WG; epilogue = 4x16B f16
//        partial stores to an exclusive per-(slice,fb,b,wave) region.
//   3. cqt_mag_part : sum 15/3/1 slice partials -> magnitude -> out
// Path A: atomic split-K (same main kernel, atomic epilogue).
// Path B: round-3 LDS-staging MFMA kernel (verified, ~224us).
// Path C: verified fp32 kernel (~370us).
//
// MFMA 16x16x32 layouts (verified rounds 3-13, absmax 4.9e-4):
//   A[m=lane&15][k=(lane>>4)*8+j], B[k=(lane>>4)*8+j][n=lane&15],
//   C/D: col=lane&15, row=(lane>>4)*4+reg.
// bp layout per 16-bin chunk (32 K-cols): 2048B = [64 lanes x 16B re][64 x 16B im]
// Partial layout: slot = ((sx*44 + fbb)*4 + wave); 2048 halfs per slot,
// lane l at slot*2048 + l*32, within-lane order [tl][r][re/im], tl=0..3.

namespace {
constexpr int kSR    = 22050;
constexpr int kHop   = 512;
constexpr int kBins  = 168;
constexpr int kT     = 689;
constexpr int kB     = 4;
constexpr int kS     = 352768;
constexpr float kKScale    = 4096.0f;
constexpr float kKScaleInv = 1.0f / 4096.0f;
constexpr int kG16 = 11;              // 16-bin groups (g10 = bins 160..167)
constexpr int kFBB = 44;              // fb(11, 64 frames each) * b(4)
constexpr int kAcc = kB * kT * kBins * 2;   // path-A split-K accumulator
// path B layout
constexpr int kTPadB   = 768;
constexpr int kBinPadB = 176;
constexpr int kAccB    = kB * kTPadB * kBinPadB * 2;
}

typedef _Float16 half8 __attribute__((ext_vector_type(8)));
typedef _Float16 half2v __attribute__((ext_vector_type(2)));
typedef float floatx4 __attribute__((ext_vector_type(4)));

struct Jobs {          // path B job table
  int k0[48];
  int lo[48];
  int hi[48];
  int n;
};

struct JobsC {         // path P/A tables
  int lo16[kG16];      // support start col per 16-bin group (256-aligned)
  int cb16[kG16];      // chunk-prefix per group (bp indexing)
  int mlo[3];          // macro-group (64-bin) support start col
  int sm[24];          // per slice: macro id
  int slo[24];         // per slice: chunk range [slo,shi) rel. to mlo
  int shi[24];
  int sbeg[3];         // first slice index of macro
  int scnt[3];         // slice count of macro
  int ns;
  int totch;
};

__device__ inline void atomAddF(float* p, float v) {
  __hip_atomic_fetch_add(p, v, __ATOMIC_RELAXED, __HIP_MEMORY_SCOPE_AGENT);
}

typedef __attribute__((address_space(3))) unsigned int lds_uint;
typedef __attribute__((address_space(1))) const unsigned int glb_uint;
__device__ __forceinline__ void dma16(const void* g, void* l) {
  __builtin_amdgcn_global_load_lds((glb_uint*)g, (lds_uint*)l, 16, 0, 0);
}

// ---- fused prep: [0,nbx) audio | [nbx,nbx+nbp) bpack | [.., +nba) zero acc ----
__global__ __launch_bounds__(256) void prep_fused(
    const float* __restrict__ x, const float* __restrict__ kr,
    const float* __restrict__ ki, _Float16* __restrict__ xp,
    _Float16* __restrict__ bp, float* __restrict__ accb,
    const int pad, const int xps, const int nmax,
    const int nbx, const int nbp, const JobsC jt) {
  int bid = blockIdx.x;
  const int tid = threadIdx.x;

  if (bid < nbx) {
    // --- padded f16 audio: 8 elements/thread, one 16B store ---
    const int octx = xps >> 3;
    const int gid = bid * 256 + tid;
    if (gid >= kB * octx) return;
    const int b = gid / octx;
    const int i = (gid - b * octx) * 8;
    const float* xb = x + (size_t)b * kS - pad;
    half8 h;
    #pragma unroll
    for (int j = 0; j < 8; ++j) {
      const int e = i + j;
      h[j] = (e >= pad && e < pad + kS) ? (_Float16)xb[e] : (_Float16)0.f;
    }
    *(half8*)&xp[(size_t)b * xps + i] = h;
    return;
  }
  bid -= nbx;

  if (bid < nbp) {
    // --- B-fragment pack: 64 threads -> one 16-bin chunk (re+im) ---
    const int chunkid = bid * 4 + (tid >> 6);
    const int lane = tid & 63;
    if (chunkid >= jt.totch) return;
    int g = 0;
    #pragma unroll
    for (int j = 1; j < kG16; ++j)
      if (chunkid >= jt.cb16[j]) g = j;
    const int c = chunkid - jt.cb16[g];
    const int mm = lane & 15;
    const int q  = lane >> 4;
    const int bin  = g * 16 + mm;
    const int col0 = jt.lo16[g] + c * 32 + q * 8;
    const bool binok = (bin < kBins);
    const float* rowr = kr + (size_t)bin * nmax;
    const float* rowi = ki + (size_t)bin * nmax;
    half8 hre, him;
    #pragma unroll
    for (int j = 0; j < 8; ++j) {
      const int col = col0 + j;
      const bool ok = binok && (col < nmax);
      hre[j] = ok ? (_Float16)(rowr[col] * kKScale) : (_Float16)0.f;
      him[j] = ok ? (_Float16)(rowi[col] * kKScale) : (_Float16)0.f;
    }
    _Float16* dst = bp + (size_t)chunkid * 1024 + lane * 8;
    *(half8*)dst = hre;
    *(half8*)(dst + 512) = him;
    return;
  }
  bid -= nbp;

  // --- zero split-K accumulator (path A only; nba=0 in path P) ---
  const int idx = (bid * 256 + tid) * 4;
  if (idx < kAcc)
    *(floatx4*)&accb[idx] = (floatx4){0.f, 0.f, 0.f, 0.f};
}

// ---- main: 4-chunk coalesced-swizzled A LDS dbuf + B reg ping-pong (R21) --
// PARTIAL=true : epilogue = exclusive f16 partial stores (no atomics)
// PARTIAL=false: epilogue = guarded agent-atomic split-K
#define BLD(S, c)                                                      \
  { const _Float16* bs_ = bgrp + (size_t)(c) * 1024;                   \
    S##0 = *(const half8*)(bs_);                                       \
    S##1 = *(const half8*)(bs_ + 512);                                 \
    S##2 = *(const half8*)(bs_ + 1024);                                \
    S##3 = *(const half8*)(bs_ + 1536);                                \
    S##4 = *(const half8*)(bs_ + 2048);                                \
    S##5 = *(const half8*)(bs_ + 2560);                                \
    S##6 = *(const half8*)(bs_ + 3072);                                \
    S##7 = *(const half8*)(bs_ + 3584); }

#define MMC(S, bufid)                                                  \
  { const _Float16* L_ = lds[bufid];                                   \
    _Pragma("unroll")                                                  \
    for (int cc = 0; cc < 4; ++cc) {                                   \
      const half8 Bre_ = (cc == 0) ? S##0 : (cc == 1) ? S##2           \
                       : (cc == 2) ? S##4 : S##6;                      \
      const half8 Bim_ = (cc == 0) ? S##1 : (cc == 1) ? S##3           \
                       : (cc == 2) ? S##5 : S##7;                      \
      const int cx_ = ((cc * 4 + q) ^ (mm & 7)) * 8;                   \
      _Pragma("unroll")                                                \
      for (int tl = 0; tl < 4; ++tl) {                                 \
        const half8 A_ = *(const half8*)(L_ + (tl * 16 + mm) * 128 + cx_); \
        accr[tl] = __builtin_amdgcn_mfma_f32_16x16x32_f16(A_, Bre_, accr[tl], 0, 0, 0); \
        acci[tl] = __builtin_amdgcn_mfma_f32_16x16x32_f16(A_, Bim_, acci[tl], 0, 0, 0); \
      } } }

template <bool PARTIAL>
__global__ __launch_bounds__(256, 4) void cqt_mfma_t(
    const _Float16* __restrict__ bp, const _Float16* __restrict__ xp,
    float* __restrict__ accb, _Float16* __restrict__ part,
    const int xps, const JobsC jt) {
  __shared__ _Float16 lds[2][8192];    // 2 x 16 KB, A only (64 rows x 128 cols)

  const int sx = blockIdx.y;
  const int fb = blockIdx.x >> 2;      // 0..10 (64 frames each)
  const int b  = blockIdx.x & 3;
  const int tid  = threadIdx.x;
  const int wave = tid >> 6;
  const int lane = tid & 63;
  const int mm = lane & 15;
  const int q  = lane >> 4;
  const int mac = jt.sm[sx];
  const int g16 = mac * 4 + wave;
  const bool gvalid = (g16 < kG16);
  const int mlo = jt.mlo[mac];
  const int gs = gvalid ? ((jt.lo16[g16] - mlo) >> 5) : 0;
  const int slo = jt.slo[sx];
  const int shi = jt.shi[sx];
  const int fbase = fb * 64;
  int cw0 = slo; if (gvalid && gs > cw0) cw0 = gs;   // wave's first chunk (mult of 8 rel slo)

  // coalesced-swizzled A source offsets (halfs), one per dma16 round
  const _Float16* xb = xp + (size_t)b * xps;
  int asrc[4];
  #pragma unroll
  for (int rd = 0; rd < 4; ++rd) {
    const int u = rd * 256 + wave * 64 + lane;
    const int r = u >> 4;                    // tile row 0..63
    int f = fbase + r; if (f > kT - 1) f = kT - 1;
    asrc[rd] = f * kHop + (((u & 15) ^ (r & 7)) * 8);
  }
  // B frags pre-packed per-lane: chunk c re at bgrp+c*1024, im at +512
  const _Float16* bgrp =
      gvalid ? (bp + (size_t)(jt.cb16[g16] - gs) * 1024 + lane * 8)
             : (bp + lane * 8);

  floatx4 accr[4], acci[4];
  #pragma unroll
  for (int tl = 0; tl < 4; ++tl) {
    accr[tl] = (floatx4){0.f, 0.f, 0.f, 0.f};
    acci[tl] = (floatx4){0.f, 0.f, 0.f, 0.f};
  }

  auto stageA = [&](int c, int buf) {
    _Float16* L = lds[buf];
    const _Float16* xc = xb + mlo + c * 32;
    #pragma unroll
    for (int rd = 0; rd < 4; ++rd)
      dma16(xc + asrc[rd], L + (rd * 256 + wave * 64) * 8);
  };

  half8 U0{}, U1{}, U2{}, U3{}, U4{}, U5{}, U6{}, U7{};
  half8 V0{}, V1{}, V2{}, V3{}, V4{}, V5{}, V6{}, V7{};

  // 4-chunk steps; step j even -> U, odd -> V; prefetch one phase ahead.
  // Slice lengths 48/40/24 chunks -> 12/10/6 steps (always even count).
  stageA(slo, 0);
  if (gvalid && cw0 == slo) BLD(U, slo);
  int buf = 0;
  int c = slo;
  #pragma unroll 1
  for (; c + 4 < shi; c += 8) {
    // phase 0: chunks [c,c+4) in U; prefetch [c+4,c+8) -> V
    __syncthreads();                     // drains A-DMA (and last B loads)
    stageA(c + 4, buf ^ 1);
    if (gvalid && c + 4 >= cw0) BLD(V, c + 4);
    __builtin_amdgcn_sched_barrier(0);   // pin B prefetch before MFMAs
    if (gvalid && c >= cw0) MMC(U, buf);
    buf ^= 1;
    // phase 1: chunks [c+4,c+8) in V; prefetch [c+8,c+12) -> U
    __syncthreads();
    if (c + 8 < shi) stageA(c + 8, buf ^ 1);
    if (gvalid && c + 8 < shi && c + 8 >= cw0) BLD(U, c + 8);
    __builtin_amdgcn_sched_barrier(0);
    if (gvalid && c + 4 >= cw0) MMC(V, buf);
    buf ^= 1;
  }

  if (PARTIAL) {
    // exclusive-region f16 partial stores: 4 x 16B per lane, no RMW
    _Float16* pw = part +
        (((size_t)sx * kFBB + blockIdx.x) * 4 + wave) * 2048 + lane * 32;
    #pragma unroll
    for (int tl = 0; tl < 4; ++tl) {
      half8 p;
      #pragma unroll
      for (int r = 0; r < 4; ++r) {
        p[r * 2]     = (_Float16)accr[tl][r];
        p[r * 2 + 1] = (_Float16)acci[tl][r];
      }
      *(half8*)(pw + tl * 8) = p;
    }
  } else {
    // guarded agent-atomic split-K combine
    const int bin = g16 * 16 + mm;
    if (gvalid && bin < kBins) {
      #pragma unroll
      for (int tl = 0; tl < 4; ++tl) {
        const int tb = fbase + tl * 16 + q * 4;
        #pragma unroll
        for (int r = 0; r < 4; ++r) {
          const int t = tb + r;
          if (t < kT) {
            const size_t o = (((size_t)b * kT + t) * kBins + bin) * 2;
            atomAddF(&accb[o],     accr[tl][r] * kKScaleInv);
            atomAddF(&accb[o + 1], acci[tl][r] * kKScaleInv);
          }
        }
      }
    }
  }
}
#undef BLD
#undef MMC

// ---- path P final: sum slice partials -> magnitude -> out ----
__global__ __launch_bounds__(256) void cqt_mag_part(
    const _Float16* __restrict__ part, float* __restrict__ out,
    const JobsC jt) {
  const int fbb = blockIdx.x;          // 0..43
  const int fb = fbb >> 2;
  const int b  = fbb & 3;
  const int wave = threadIdx.x >> 6;
  const int lane = threadIdx.x & 63;
  const int g16 = blockIdx.y * 4 + wave;
  if (g16 >= kG16) return;
  const int mac = g16 >> 2;
  const int w   = g16 & 3;
  const int mm = lane & 15;
  const int q  = lane >> 4;

  float a[32];
  #pragma unroll
  for (int i = 0; i < 32; ++i) a[i] = 0.f;
  const int s0 = jt.sbeg[mac];
  const int s1 = s0 + jt.scnt[mac];
  #pragma unroll 1
  for (int s = s0; s < s1; ++s) {
    const _Float16* p = part +
        (((size_t)s * kFBB + fbb) * 4 + w) * 2048 + lane * 32;
    #pragma unroll
    for (int tl = 0; tl < 4; ++tl) {
      const half8 v = *(const half8*)(p + tl * 8);
      #pragma unroll
      for (int j = 0; j < 8; ++j) a[tl * 8 + j] += (float)v[j];
    }
  }
  const int k = g16 * 16 + mm;
  if (k >= kBins) return;
  #pragma unroll
  for (int tl = 0; tl < 4; ++tl) {
    #pragma unroll
    for (int r = 0; r < 4; ++r) {
      const int t = fb * 64 + tl * 16 + q * 4 + r;
      if (t < kT) {
        const float re = a[tl * 8 + r * 2];
        const float im = a[tl * 8 + r * 2 + 1];
        out[((size_t)b * kT + t) * kBins + k] =
            sqrtf(re * re + im * im) * kKScaleInv;
      }
    }
  }
}

// ---- path A final: magnitude, 4 outputs/thread ----
__global__ __launch_bounds__(256) void cqt_mag4(
    const float* __restrict__ accb, float* __restrict__ out) {
  const int gid = (blockIdx.x * 256 + threadIdx.x) * 4;
  if (gid >= kB * kT * kBins) return;
  const floatx4 v0 = *(const floatx4*)&accb[gid * 2];
  const floatx4 v1 = *(const floatx4*)&accb[gid * 2 + 4];
  floatx4 o;
  o[0] = sqrtf(v0[0] * v0[0] + v0[1] * v0[1]);
  o[1] = sqrtf(v0[2] * v0[2] + v0[3] * v0[3]);
  o[2] = sqrtf(v1[0] * v1[0] + v1[1] * v1[1]);
  o[3] = sqrtf(v1[2] * v1[2] + v1[3] * v1[3]);
  *(floatx4*)&out[gid] = o;
}

// ---- path B final: magnitude (layout-parametric) ----
__global__ __launch_bounds__(256) void cqt_mag_final(
    const float* __restrict__ accb, float* __restrict__ out,
    const int tp, const int kp) {
  int gid = blockIdx.x * 256 + threadIdx.x;
  if (gid >= kB * kT * kBins) return;
  const int k = gid % kBins;
  const int r = gid / kBins;
  const int t = r % kT;
  const int b = r / kT;
  const float2 v = ((const float2*)accb)[((size_t)b * tp + t) * kp + k];
  out[gid] = sqrtf(v.x * v.x + v.y * v.y);
}

// ================= path B: round-3 LDS-staging MFMA (verified) =============
__global__ __launch_bounds__(256) void prep_x_kernel(
    const float* __restrict__ x, _Float16* __restrict__ xp,
    const int pad, const int xps) {
  const int halfx = xps >> 1;
  int gid = blockIdx.x * 256 + threadIdx.x;
  if (gid >= kB * halfx) return;
  const int b = gid / halfx;
  const int i = (gid - b * halfx) * 2;
  float v0 = 0.f, v1 = 0.f;
  if (i     >= pad && i     < pad + kS) v0 = x[(size_t)b * kS + (i - pad)];
  if (i + 1 >= pad && i + 1 < pad + kS) v1 = x[(size_t)b * kS + (i + 1 - pad)];
  half2v h; h.x = (_Float16)v0; h.y = (_Float16)v1;
  *(half2v*)&xp[(size_t)b * xps + i] = h;
}

__global__ __launch_bounds__(256) void cqt_mfma_kernel(
    const float* __restrict__ kr, const float* __restrict__ ki,
    const _Float16* __restrict__ xp, float* __restrict__ accb,
    const int nmax, const int xps, const Jobs jt) {
  __shared__ _Float16 Bs[2][16][264];
  const int jb = blockIdx.x;
  const int k0   = jt.k0[jb];
  const int n_lo = jt.lo[jb];
  const int n_hi = jt.hi[jb];
  const int b  = blockIdx.z;
  const int fb = blockIdx.y;
  const int tid  = threadIdx.x;
  const int lane = tid & 63;
  const int wave = tid >> 6;
  const int m = lane & 15;
  const int q = lane >> 4;
  const int sbin = tid >> 4;
  const int scol = tid & 15;
  const int gbin = k0 + sbin;
  const bool binok = (gbin < kBins);
  const float* rowr = kr + (size_t)gbin * nmax;
  const float* rowi = ki + (size_t)gbin * nmax;
  const int fbase = fb * 256 + wave * 64;
  const _Float16* ax =
      xp + (size_t)b * xps + (size_t)(fbase + m) * kHop + q * 8;
  floatx4 accr[4], acci[4];
  #pragma unroll
  for (int tl = 0; tl < 4; ++tl) {
    accr[tl] = (floatx4){0.f, 0.f, 0.f, 0.f};
    acci[tl] = (floatx4){0.f, 0.f, 0.f, 0.f};
  }
  for (int n0r = n_lo; n0r < n_hi; n0r += 256) {
    __syncthreads();
    #pragma unroll
    for (int c = 0; c < 16; ++c) {
      const int col = n0r + scol + c * 16;
      const bool ok = binok && (col < nmax);
      const float vr = ok ? rowr[col] : 0.f;
      const float vi = ok ? rowi[col] : 0.f;
      Bs[0][sbin][scol + c * 16] = (_Float16)(vr * kKScale);
      Bs[1][sbin][scol + c * 16] = (_Float16)(vi * kKScale);
    }
    __syncthreads();
    const _Float16* axr = ax + n0r;
    #pragma unroll
    for (int c = 0; c < 8; ++c) {
      const int ko = c * 32 + q * 8;
      const half8 br = *(const half8*)&Bs[0][m][ko];
      const half8 bi = *(const half8*)&Bs[1][m][ko];
      #pragma unroll
      for (int tl = 0; tl < 4; ++tl) {
        const half8 a = *(const half8*)(axr + tl * 16 * kHop + c * 32);
        accr[tl] = __builtin_amdgcn_mfma_f32_16x16x32_f16(a, br, accr[tl], 0, 0, 0);
        acci[tl] = __builtin_amdgcn_mfma_f32_16x16x32_f16(a, bi, acci[tl], 0, 0, 0);
      }
    }
  }
  #pragma unroll
  for (int tl = 0; tl < 4; ++tl) {
    #pragma unroll
    for (int rr = 0; rr < 4; ++rr) {
      const int t = fbase + tl * 16 + q * 4 + rr;
      const size_t o = (((size_t)b * kTPadB + t) * kBinPadB + (k0 + m)) * 2;
      atomAddF(&accb[o],     accr[tl][rr] * kKScaleInv);
      atomAddF(&accb[o + 1], acci[tl][rr] * kKScaleInv);
    }
  }
}

// ================= path C: verified fp32 kernel (round 2) ==================
namespace fb32 {
constexpr int TT = 8;
constexpr int KG = 4;
constexpr int kTTiles  = (kT + TT - 1) / TT;
constexpr int kKGroups = kBins / KG;
constexpr int kWaves   = kB * kTTiles * kKGroups;
}

__global__ __launch_bounds__(256) void cqt_mag_kernel(
    const float* __restrict__ x,
    const float* __restrict__ kr,
    const float* __restrict__ ki,
    float* __restrict__ out,
    const int nmax, const int pad) {
  using namespace fb32;
  const int wave = (blockIdx.x << 2) + (threadIdx.x >> 6);
  const int lane = threadIdx.x & 63;
  if (wave >= kWaves) return;
  const int kg    = wave / (kB * kTTiles);
  const int rem   = wave - kg * (kB * kTTiles);
  const int b     = rem / kTTiles;
  const int ttile = rem - b * kTTiles;
  const int k0 = kg * KG;
  const int t0 = ttile * TT;
  const double Q  = 1.0 / (exp2(1.0 / 24.0) - 1.0);
  const double f0 = 32.7 * exp2((double)k0 / 24.0);
  int N = (int)ceil(Q * (double)kSR / f0) + 8;
  int full_start = nmax - N;
  if (full_start < 0) full_start = 0;
  int tbase[TT], lo[TT], t_last;
  { int t = t0 + TT - 1; if (t > kT - 1) t = kT - 1; t_last = t; }
  #pragma unroll
  for (int tt = 0; tt < TT; ++tt) {
    int t = t0 + tt; if (t > kT - 1) t = kT - 1;
    tbase[tt] = b * kS + t * kHop - pad;
    lo[tt]    = pad - t * kHop;
  }
  int head_start = pad - t_last * kHop;
  if (head_start < full_start) head_start = full_start;
  int safe = pad - t0 * kHop;
  if (safe < head_start) safe = head_start;
  int body_start = nmax - ((nmax - safe) & ~63);
  float accr[TT][KG], acci[TT][KG];
  #pragma unroll
  for (int tt = 0; tt < TT; ++tt)
    #pragma unroll
    for (int kk = 0; kk < KG; ++kk) { accr[tt][kk] = 0.f; acci[tt][kk] = 0.f; }
  for (int n = body_start - 64; n > head_start - 64; n -= 64) {
    const int nn = n + lane;
    const bool kok = (nn >= 0);
    float krv[KG], kiv[KG];
    #pragma unroll
    for (int kk = 0; kk < KG; ++kk) {
      krv[kk] = kok ? kr[(k0 + kk) * nmax + nn] : 0.f;
      kiv[kk] = kok ? ki[(k0 + kk) * nmax + nn] : 0.f;
    }
    float a[TT];
    #pragma unroll
    for (int tt = 0; tt < TT; ++tt)
      a[tt] = (nn >= lo[tt]) ? x[tbase[tt] + nn] : 0.f;
    #pragma unroll
    for (int tt = 0; tt < TT; ++tt)
      #pragma unroll
      for (int kk = 0; kk < KG; ++kk) {
        accr[tt][kk] = fmaf(a[tt], krv[kk], accr[tt][kk]);
        acci[tt][kk] = fmaf(a[tt], kiv[kk], acci[tt][kk]);
      }
  }
  for (int n = body_start; n < nmax; n += 64) {
    const int nn = n + lane;
    float krv[KG], kiv[KG];
    #pragma unroll
    for (int kk = 0; kk < KG; ++kk) {
      krv[kk] = kr[(k0 + kk) * nmax + nn];
      kiv[kk] = ki[(k0 + kk) * nmax + nn];
    }
    float a[TT];
    #pragma unroll
    for (int tt = 0; tt < TT; ++tt)
      a[tt] = x[tbase[tt] + nn];
    #pragma unroll
    for (int tt = 0; tt < TT; ++tt)
      #pragma unroll
      for (int kk = 0; kk < KG; ++kk) {
        accr[tt][kk] = fmaf(a[tt], krv[kk], accr[tt][kk]);
        acci[tt][kk] = fmaf(a[tt], kiv[kk], acci[tt][kk]);
      }
  }
  #pragma unroll
  for (int tt = 0; tt < TT; ++tt) {
    #pragma unroll
    for (int kk = 0; kk < KG; ++kk) {
      float r = accr[tt][kk];
      float i = acci[tt][kk];
      #pragma unroll
      for (int s = 32; s > 0; s >>= 1) {
        r += __shfl_xor(r, s, 64);
        i += __shfl_xor(i, s, 64);
      }
      if (lane == 0) {
        const int t = t0 + tt;
        if (t < kT)
          out[(b * kT + t) * kBins + (k0 + kk)] = sqrtf(r * r + i * i);
      }
    }
  }
}
// ============================================================================

extern "C" void kernel_launch(void* const* d_in, const int* in_sizes, int n_in,
                              void* d_out, int out_size, void* d_ws, size_t ws_size,
                              hipStream_t stream) {
  const float* x  = (const float*)d_in[0];   // [4, 1, 352768]
  const float* kr = (const float*)d_in[1];   // [168, nmax]
  const float* ki = (const float*)d_in[2];   // [168, nmax]
  float* out = (float*)d_out;                // [4, 1, 689, 168]

  const int nmax = in_sizes[1] / kBins;      // 23013 (runtime truth)
  const int pad  = nmax - kHop;

  const int kcap = ((nmax + 255) / 256) * 256;   // 23040
  const double Q = 1.0 / (exp2(1.0 / 24.0) - 1.0);

  // ---- path P/A tables ----
  JobsC jc;
  int tot = 0;
  for (int g = 0; g < kG16; ++g) {
    const double f0 = 32.7 * exp2((double)(16 * g) / 24.0);
    const int N = (int)ceil(Q * (double)kSR / f0) + 8;
    int lo = nmax - N;
    if (lo < 0) lo = 0;
    lo &= ~255;
    jc.lo16[g] = lo;
    jc.cb16[g] = tot;
    tot += (kcap - lo) / 32;
  }
  jc.totch = tot;                        // ~1984 chunks
  // ns=19 slice table (48-chunk slices -> 15/3/1; lengths 48/40/24 are all
  // divisible by 8, required by the 4-chunk-step U/V pair loop)
  int ns = 0;
  for (int m = 0; m < 3; ++m) {
    jc.mlo[m] = jc.lo16[4 * m];
    jc.sbeg[m] = ns;
    const int C = (kcap - jc.mlo[m]) / 32;       // 720 / 120 / 24
    const int nsl = (C + 47) / 48;               // 15 / 3 / 1
    const int len = ((C + nsl - 1) / nsl + 1) & ~1;
    for (int s = 0; s < nsl && ns < 24; ++s) {
      const int lo = s * len;
      if (lo >= C) break;
      int hi = lo + len;
      if (hi > C) hi = C;
      jc.sm[ns] = m; jc.slo[ns] = lo; jc.shi[ns] = hi;
      ++ns;
    }
    jc.scnt[m] = ns - jc.sbeg[m];
  }
  jc.ns = ns;                            // 19 expected

  // ---- shared ws pieces ----
  const int xpsA = (kT - 1) * kHop + kcap + 256;           // 375,552 (%8==0)
  const size_t xpA_bytes = (size_t)kB * xpsA * sizeof(_Float16);
  const size_t bpA_bytes = (size_t)tot * 2048;

  // path P layout: xp | part(f16) | bp
  const size_t partP_off   = (xpA_bytes + 511) & ~(size_t)511;
  const size_t partP_bytes = (size_t)ns * kFBB * 4 * 2048 * sizeof(_Float16);
  const size_t bpP_off     = (partP_off + partP_bytes + 511) & ~(size_t)511;
  const size_t ws_P = bpP_off + bpA_bytes;                 // ~20.8 MB

  // path A layout: xp | acc(f32) | bp
  const size_t accA_off  = (xpA_bytes + 511) & ~(size_t)511;
  const size_t accA_bytes = (size_t)kAcc * sizeof(float);
  const size_t bpA_off   = (accA_off + accA_bytes + 511) & ~(size_t)511;
  const size_t ws_A = bpA_off + bpA_bytes;                 // ~10.8 MB

  // path B layout
  const int xpsB = (kTPadB - 1) * kHop + kcap + 256;
  const size_t xpB_bytes = (size_t)kB * xpsB * sizeof(_Float16);
  const size_t accB_off  = (xpB_bytes + 511) & ~(size_t)511;
  const size_t accB_bytes = (size_t)kAccB * sizeof(float);
  const size_t ws_B = accB_off + accB_bytes;

  const int nbx = (kB * (xpsA / 8) + 255) / 256;   // audio blocks (8 el/thr)
  const int nbp = (tot + 3) / 4;                   // bpack blocks (4 chunks ea)

  if (ws_size >= ws_P) {
    // ---- path P: partial-store split-K, no atomics ----
    _Float16* xp   = (_Float16*)d_ws;
    _Float16* part = (_Float16*)((char*)d_ws + partP_off);
    _Float16* bp   = (_Float16*)((char*)d_ws + bpP_off);

    prep_fused<<<nbx + nbp, 256, 0, stream>>>(
        x, kr, ki, xp, bp, (float*)part /*unused*/, pad, xpsA, nmax,
        nbx, nbp, jc);
    {
      dim3 grid(kFBB, ns);
      cqt_mfma_t<true><<<grid, 256, 0, stream>>>(
          bp, xp, nullptr, part, xpsA, jc);
    }
    {
      dim3 grid(kFBB, 3);    // 11 g16 waves per (fb,b) in 3 4-wave WGs
      cqt_mag_part<<<grid, 256, 0, stream>>>(part, out, jc);
    }
    return;
  }

  if (ws_size >= ws_A) {
    // ---- path A: atomic split-K ----
    _Float16* xp = (_Float16*)d_ws;
    float* accb  = (float*)((char*)d_ws + accA_off);
    _Float16* bp = (_Float16*)((char*)d_ws + bpA_off);

    const int nba = (kAcc / 4 + 255) / 256;
    prep_fused<<<nbx + nbp + nba, 256, 0, stream>>>(
        x, kr, ki, xp, bp, accb, pad, xpsA, nmax, nbx, nbp, jc);
    {
      dim3 grid(kFBB, ns);
      cqt_mfma_t<false><<<grid, 256, 0, stream>>>(
          bp, xp, accb, nullptr, xpsA, jc);
    }
    {
      const int total = kB * kT * kBins;
      cqt_mag4<<<(total / 4 + 255) / 256, 256, 0, stream>>>(accb, out);
    }
    return;
  }

  if (ws_size >= ws_B) {
    // ---- path B (round-3, verified ~224us) ----
    _Float16* xp = (_Float16*)d_ws;
    float* accb  = (float*)((char*)d_ws + accB_off);
    Jobs jt;
    int nj = 0;
    for (int g = 0; g < 11; ++g) {
      const int gk0 = 16 * g;
      const double f0 = 32.7 * exp2((double)gk0 / 24.0);
      const int N = (int)ceil(Q * (double)kSR / f0) + 8;
      int lo = nmax - N;
      if (lo < 0) lo = 0;
      lo = (lo / 2048) * 2048;
      for (int s = lo; s < kcap && nj < 48; s += 2048) {
        jt.k0[nj] = gk0;
        jt.lo[nj] = s;
        jt.hi[nj] = (s + 2048 < kcap) ? s + 2048 : kcap;
        ++nj;
      }
    }
    jt.n = nj;
    hipMemsetAsync(accb, 0, accB_bytes, stream);
    {
      const int total = kB * (xpsB / 2);
      prep_x_kernel<<<(total + 255) / 256, 256, 0, stream>>>(x, xp, pad, xpsB);
    }
    {
      dim3 grid(nj, kTPadB / 256, kB);
      cqt_mfma_kernel<<<grid, 256, 0, stream>>>(kr, ki, xp, accb, nmax, xpsB, jt);
    }
    {
      const int total = kB * kT * kBins;
      cqt_mag_final<<<(total + 255) / 256, 256, 0, stream>>>(
          accb, out, kTPadB, kBinPadB);
    }
    return;
  }

  // ---- path C: fp32 fallback ----
  {
    const int blocks = fb32::kWaves / 4;
    cqt_mag_kernel<<<blocks, 256, 0, stream>>>(x, kr, ki, out, nmax, pad);
  }
}